// Round 1
// baseline (3550.510 us; speedup 1.0000x reference)
//
#include <hip/hip_runtime.h>
#include <hip/hip_bf16.h>

#define VOCAB 10000
#define HID   1024
#define OUTN  10000
#define BATCH 32
#define SEQT  256
#define NPAD  10112   // 79*128

typedef short s16x8 __attribute__((ext_vector_type(8)));
typedef float f32x4 __attribute__((ext_vector_type(4)));

#define GLOAD_LDS16(gptr, lptr)                                                      \
  __builtin_amdgcn_global_load_lds((__attribute__((address_space(1))) void*)(gptr),  \
                                   (__attribute__((address_space(3))) void*)(lptr),  \
                                   16, 0, 0)

// ---------------------------------------------------------------- transpose+cast
// src [K][N] f32 row-major  ->  dst [Npad][K] bf16 (rows n>=N zero-filled)
__global__ __launch_bounds__(256) void transpose_cast(
    const float* __restrict__ src, __hip_bfloat16* __restrict__ dst,
    int K, int N, int Npad) {
  __shared__ float tile[32][33];
  const int n0 = blockIdx.x * 32, k0 = blockIdx.y * 32;
  const int tx = threadIdx.x & 31, ty = threadIdx.x >> 5;  // 32 x 8
#pragma unroll
  for (int yy = 0; yy < 32; yy += 8) {
    const int k = k0 + ty + yy, n = n0 + tx;
    tile[ty + yy][tx] = (k < K && n < N) ? src[k * N + n] : 0.f;
  }
  __syncthreads();
#pragma unroll
  for (int yy = 0; yy < 32; yy += 8) {
    const int n = n0 + ty + yy, k = k0 + tx;
    if (n < Npad && k < K) dst[(size_t)n * K + k] = __float2bfloat16(tile[tx][ty + yy]);
  }
}

__global__ __launch_bounds__(256) void cast_state(
    const float* __restrict__ s, __hip_bfloat16* __restrict__ d, int n) {
  const int i = blockIdx.x * 256 + threadIdx.x;
  if (i < n) d[i] = __float2bfloat16(s[i]);
}

// ---------------------------------------------------------------- recurrence step
// Hnext[b][j] = tanh(W_xh[ids[b][t]][j] + sum_k Hprev[b][k]*WhhT[j][k] + b_h[j])
// grid 32 WGs x 256 thr; WG owns 32 cols; waves 2x2 over (32 rows x 32 cols)
__global__ __launch_bounds__(256) void rnn_step(
    const __hip_bfloat16* __restrict__ Hprev,   // [32][1024] bf16
    __hip_bfloat16* __restrict__ Hnext,         // [32][1024] bf16
    const int* __restrict__ ids,                // [BATCH][SEQT]
    const float* __restrict__ W_xh,             // [VOCAB][HID] f32
    const __hip_bfloat16* __restrict__ WhhT,    // [HID][HID] bf16, [n][k]
    const float* __restrict__ b_h,
    float* __restrict__ Hfinal,                 // nullptr except last step
    int t) {
  const int wg   = blockIdx.x;
  const int wave = threadIdx.x >> 6;
  const int lane = threadIdx.x & 63;
  const int wm = wave >> 1, wn = wave & 1;
  const int row0 = wm * 16;
  const int col0 = wg * 32 + wn * 16;
  const int l16 = lane & 15;
  const int lk  = (lane >> 4) * 8;

  const __hip_bfloat16* aBase = Hprev + (row0 + l16) * HID + lk;
  const __hip_bfloat16* bBase = WhhT + (size_t)(col0 + l16) * HID + lk;

  f32x4 acc = {0.f, 0.f, 0.f, 0.f};
#pragma unroll 4
  for (int k0 = 0; k0 < HID; k0 += 32) {
    s16x8 a = *reinterpret_cast<const s16x8*>(aBase + k0);
    s16x8 b = *reinterpret_cast<const s16x8*>(bBase + k0);
    acc = __builtin_amdgcn_mfma_f32_16x16x32_bf16(a, b, acc, 0, 0, 0);
  }

  // C/D layout: col = lane&15, row = (lane>>4)*4 + j   [m89]
  const int ccol  = col0 + l16;
  const int crow0 = row0 + (lane >> 4) * 4;
  const float bh = b_h[ccol];
#pragma unroll
  for (int j = 0; j < 4; ++j) {
    const int r = crow0 + j;                       // batch row 0..31
    const int id = ids[r * SEQT + t];
    const float v = tanhf(acc[j] + W_xh[(size_t)id * HID + ccol] + bh);
    Hnext[r * HID + ccol] = __float2bfloat16(v);
    if (Hfinal) Hfinal[r * HID + ccol] = v;
  }
}

// ---------------------------------------------------------------- output GEMM
// Y[r][n] = sum_k A[r][k]*BT[n][k] + b_q[n]; A=[8192][1024], BT=[10112][1024]
// 128x128 tile, BK=64, 4 waves (2x2, 64x64 each, 4x4 frags of 16x16)
__global__ __launch_bounds__(256) void gemm_out(
    const __hip_bfloat16* __restrict__ A,
    const __hip_bfloat16* __restrict__ BT,
    const float* __restrict__ b_q,
    float* __restrict__ Y) {
  __shared__ __align__(16) __hip_bfloat16 As[128 * 64];
  __shared__ __align__(16) __hip_bfloat16 Bs[128 * 64];

  const int bx = blockIdx.x;   // n tile 0..78
  const int by = blockIdx.y;   // m tile 0..63
  const int wave = threadIdx.x >> 6;
  const int lane = threadIdx.x & 63;
  const int wm = wave >> 1, wn = wave & 1;
  const int l16 = lane & 15;

  const size_t aRow0 = (size_t)by * 128;
  const size_t bRow0 = (size_t)bx * 128;

  f32x4 acc[4][4];
#pragma unroll
  for (int m = 0; m < 4; ++m)
#pragma unroll
    for (int n = 0; n < 4; ++n) acc[m][n] = (f32x4){0.f, 0.f, 0.f, 0.f};

  for (int kt = 0; kt < HID / 64; ++kt) {
    __syncthreads();
    // stage: LDS linear dest, inverse-swizzled global source (rule 21)
#pragma unroll
    for (int q = 0; q < 4; ++q) {
      const int ci = q * 256 + wave * 64 + lane;   // chunk 0..1023 (16B each)
      const int r  = ci >> 3;                      // tile row 0..127
      const int gc = (ci & 7) ^ (r & 7);           // swizzled source chunk
      const __hip_bfloat16* ga = A  + (aRow0 + r) * HID + kt * 64 + gc * 8;
      const __hip_bfloat16* gb = BT + (bRow0 + r) * HID + kt * 64 + gc * 8;
      GLOAD_LDS16(ga, &As[(q * 256 + wave * 64) * 8]);
      GLOAD_LDS16(gb, &Bs[(q * 256 + wave * 64) * 8]);
    }
    __syncthreads();

    s16x8 af[2][4], bf[2][4];
#pragma unroll
    for (int kc = 0; kc < 2; ++kc) {
      const int cc = kc * 4 + (lane >> 4);
#pragma unroll
      for (int m = 0; m < 4; ++m) {
        const int rowA = wm * 64 + m * 16 + l16;
        af[kc][m] = *reinterpret_cast<const s16x8*>(&As[rowA * 64 + ((cc ^ (rowA & 7)) * 8)]);
      }
#pragma unroll
      for (int n = 0; n < 4; ++n) {
        const int rowB = wn * 64 + n * 16 + l16;
        bf[kc][n] = *reinterpret_cast<const s16x8*>(&Bs[rowB * 64 + ((cc ^ (rowB & 7)) * 8)]);
      }
    }
#pragma unroll
    for (int kc = 0; kc < 2; ++kc)
#pragma unroll
      for (int m = 0; m < 4; ++m)
#pragma unroll
        for (int n = 0; n < 4; ++n)
          acc[m][n] = __builtin_amdgcn_mfma_f32_16x16x32_bf16(af[kc][m], bf[kc][n], acc[m][n], 0, 0, 0);
  }

  const int crow0 = by * 128 + wm * 64 + (lane >> 4) * 4;
  const int ccol0 = bx * 128 + wn * 64 + l16;
#pragma unroll
  for (int n = 0; n < 4; ++n) {
    const int ccol = ccol0 + n * 16;
    if (ccol < OUTN) {
      const float bq = b_q[ccol];
#pragma unroll
      for (int m = 0; m < 4; ++m) {
        const int crow = crow0 + m * 16;
#pragma unroll
        for (int j = 0; j < 4; ++j)
          Y[(size_t)(crow + j) * OUTN + ccol] = acc[m][n][j] + bq;
      }
    }
  }
}

// ---------------------------------------------------------------- launch
extern "C" void kernel_launch(void* const* d_in, const int* in_sizes, int n_in,
                              void* d_out, int out_size, void* d_ws, size_t ws_size,
                              hipStream_t stream) {
  const int*   inputs = (const int*)d_in[0];
  const float* state  = (const float*)d_in[1];
  const float* W_xh   = (const float*)d_in[2];
  const float* W_hh   = (const float*)d_in[3];
  const float* b_h    = (const float*)d_in[4];
  const float* W_hq   = (const float*)d_in[5];
  const float* b_q    = (const float*)d_in[6];

  float* Y    = (float*)d_out;                        // [8192][10000]
  float* Hfin = Y + (size_t)SEQT * BATCH * OUTN;      // [32][1024]

  char* ws = (char*)d_ws;
  // Hbf: 257 slots of [32][1024] bf16; slot 0 = state, slot t+1 = H_t
  __hip_bfloat16* Hbf  = (__hip_bfloat16*)ws;                                   // 16,842,752 B
  __hip_bfloat16* WhhT = (__hip_bfloat16*)(ws + 16842752);                      //  2,097,152 B
  __hip_bfloat16* WhqT = (__hip_bfloat16*)(ws + 16842752 + 2097152);            // 20,709,376 B

  transpose_cast<<<dim3(32, 32), 256, 0, stream>>>(W_hh, WhhT, HID, HID, HID);
  transpose_cast<<<dim3(NPAD / 32, 32), 256, 0, stream>>>(W_hq, WhqT, HID, OUTN, NPAD);
  cast_state<<<dim3(BATCH * HID / 256), 256, 0, stream>>>(state, Hbf, BATCH * HID);

  for (int t = 0; t < SEQT; ++t) {
    rnn_step<<<dim3(32), 256, 0, stream>>>(
        Hbf + (size_t)t * BATCH * HID,
        Hbf + (size_t)(t + 1) * BATCH * HID,
        inputs, W_xh, WhhT, b_h,
        (t == SEQT - 1) ? Hfin : (float*)nullptr, t);
  }

  // A rows r = t*32+b  <->  Hbf slot t+1 row b  ==  Hbf + (r+32)*1024
  gemm_out<<<dim3(NPAD / 128, 8192 / 128), 256, 0, stream>>>(Hbf + BATCH * HID, WhqT, b_q, Y);
}

// Round 2
// 3041.590 us; speedup vs baseline: 1.1673x; 1.1673x over previous
//
#include <hip/hip_runtime.h>
#include <hip/hip_bf16.h>
#include <hip/hip_cooperative_groups.h>

namespace cg = cooperative_groups;

#define VOCAB 10000
#define HID   1024
#define OUTN  10000
#define BATCH 32
#define SEQT  256
#define NPAD  10112   // 79*128

typedef short s16x8 __attribute__((ext_vector_type(8)));
typedef float f32x4 __attribute__((ext_vector_type(4)));

#define GLOAD_LDS16(gptr, lptr)                                                      \
  __builtin_amdgcn_global_load_lds((__attribute__((address_space(1))) void*)(gptr),  \
                                   (__attribute__((address_space(3))) void*)(lptr),  \
                                   16, 0, 0)

// ---------------------------------------------------------------- transpose+cast
// src [K][N] f32 row-major  ->  dst [Npad][K] bf16 (rows n>=N zero-filled)
__global__ __launch_bounds__(256) void transpose_cast(
    const float* __restrict__ src, __hip_bfloat16* __restrict__ dst,
    int K, int N, int Npad) {
  __shared__ float tile[32][33];
  const int n0 = blockIdx.x * 32, k0 = blockIdx.y * 32;
  const int tx = threadIdx.x & 31, ty = threadIdx.x >> 5;  // 32 x 8
#pragma unroll
  for (int yy = 0; yy < 32; yy += 8) {
    const int k = k0 + ty + yy, n = n0 + tx;
    tile[ty + yy][tx] = (k < K && n < N) ? src[k * N + n] : 0.f;
  }
  __syncthreads();
#pragma unroll
  for (int yy = 0; yy < 32; yy += 8) {
    const int n = n0 + ty + yy, k = k0 + tx;
    if (n < Npad && k < K) dst[(size_t)n * K + k] = __float2bfloat16(tile[tx][ty + yy]);
  }
}

__global__ __launch_bounds__(256) void cast_state(
    const float* __restrict__ s, __hip_bfloat16* __restrict__ d, int n) {
  const int i = blockIdx.x * 256 + threadIdx.x;
  if (i < n) d[i] = __float2bfloat16(s[i]);
}

// ---------------------------------------------------------------- persistent recurrence
// One cooperative kernel does all 256 steps. 32 WGs x 4 waves; WG owns 32 cols,
// waves 2x2 over (32 rows x 32 cols). WhhT slice lives in registers (128 VGPR).
// H slot t+1 = tanh(W_xh[ids[:,t]] + H_t @ W_hh + b_h); one grid.sync per step.
__global__ __launch_bounds__(256, 1) void rnn_persist(
    __hip_bfloat16* __restrict__ Hbf,          // 257 slots of [32][1024] bf16
    const int* __restrict__ ids,               // [BATCH][SEQT]
    const float* __restrict__ W_xh,            // [VOCAB][HID] f32
    const __hip_bfloat16* __restrict__ WhhT,   // [HID][HID] bf16, [n][k]
    const float* __restrict__ b_h,
    float* __restrict__ Hfin) {                // [32][1024] f32 (tail of d_out)
  cg::grid_group grid = cg::this_grid();

  const int wg   = blockIdx.x;
  const int wave = threadIdx.x >> 6;
  const int lane = threadIdx.x & 63;
  const int wm = wave >> 1, wn = wave & 1;
  const int row0 = wm * 16;
  const int col0 = wg * 32 + wn * 16;
  const int l16 = lane & 15;
  const int g   = lane >> 4;

  // ---- hoist B (WhhT slice) into registers: 32 frags = 128 VGPR
  s16x8 breg[32];
  {
    const __hip_bfloat16* bBase = WhhT + (size_t)(col0 + l16) * HID + g * 8;
#pragma unroll
    for (int kk = 0; kk < 32; ++kk)
      breg[kk] = *reinterpret_cast<const s16x8*>(bBase + kk * 32);
  }

  // C/D layout: col = lane&15, row = (lane>>4)*4 + j   [m89]
  const int ccol  = col0 + l16;
  const int crow0 = row0 + g * 4;
  const float bh = b_h[ccol];

  // ---- prefetch W_xh gather for t=0
  float wxh[4];
#pragma unroll
  for (int j = 0; j < 4; ++j)
    wxh[j] = W_xh[(size_t)ids[(crow0 + j) * SEQT + 0] * HID + ccol];

  const int aOff = (row0 + l16) * HID + g * 8;

  for (int t = 0; t < SEQT; ++t) {
    const __hip_bfloat16* aBase = Hbf + (size_t)t * BATCH * HID + aOff;
    __hip_bfloat16* Hnext = Hbf + (size_t)(t + 1) * BATCH * HID;

    // issue all 32 independent A loads (L2/L3-resident, one latency + drain)
    s16x8 areg[32];
#pragma unroll
    for (int kk = 0; kk < 32; ++kk)
      areg[kk] = *reinterpret_cast<const s16x8*>(aBase + kk * 32);

    f32x4 acc0 = {0.f, 0.f, 0.f, 0.f}, acc1 = {0.f, 0.f, 0.f, 0.f};
#pragma unroll
    for (int kk = 0; kk < 32; kk += 2) {
      acc0 = __builtin_amdgcn_mfma_f32_16x16x32_bf16(areg[kk],     breg[kk],     acc0, 0, 0, 0);
      acc1 = __builtin_amdgcn_mfma_f32_16x16x32_bf16(areg[kk + 1], breg[kk + 1], acc1, 0, 0, 0);
    }

#pragma unroll
    for (int j = 0; j < 4; ++j) {
      const float v = tanhf(acc0[j] + acc1[j] + wxh[j] + bh);
      Hnext[(crow0 + j) * HID + ccol] = __float2bfloat16(v);
      if (t == SEQT - 1) Hfin[(crow0 + j) * HID + ccol] = v;
    }

    // prefetch next step's W_xh gather (H-independent) — in flight across sync
    if (t + 1 < SEQT) {
#pragma unroll
      for (int j = 0; j < 4; ++j)
        wxh[j] = W_xh[(size_t)ids[(crow0 + j) * SEQT + (t + 1)] * HID + ccol];
    }

    grid.sync();
  }
}

// ---------------------------------------------------------------- output GEMM
// Y[r][n] = sum_k A[r][k]*BT[n][k] + b_q[n]; A=[8192][1024], BT=[10112][1024]
// 128x128 tile, BK=64, 4 waves (2x2, 64x64 each, 4x4 frags of 16x16)
__global__ __launch_bounds__(256) void gemm_out(
    const __hip_bfloat16* __restrict__ A,
    const __hip_bfloat16* __restrict__ BT,
    const float* __restrict__ b_q,
    float* __restrict__ Y) {
  __shared__ __align__(16) __hip_bfloat16 As[128 * 64];
  __shared__ __align__(16) __hip_bfloat16 Bs[128 * 64];

  const int bx = blockIdx.x;   // n tile 0..78
  const int by = blockIdx.y;   // m tile 0..63
  const int wave = threadIdx.x >> 6;
  const int lane = threadIdx.x & 63;
  const int wm = wave >> 1, wn = wave & 1;
  const int l16 = lane & 15;

  const size_t aRow0 = (size_t)by * 128;
  const size_t bRow0 = (size_t)bx * 128;

  f32x4 acc[4][4];
#pragma unroll
  for (int m = 0; m < 4; ++m)
#pragma unroll
    for (int n = 0; n < 4; ++n) acc[m][n] = (f32x4){0.f, 0.f, 0.f, 0.f};

  for (int kt = 0; kt < HID / 64; ++kt) {
    __syncthreads();
    // stage: LDS linear dest, inverse-swizzled global source (rule 21)
#pragma unroll
    for (int q = 0; q < 4; ++q) {
      const int ci = q * 256 + wave * 64 + lane;   // chunk 0..1023 (16B each)
      const int r  = ci >> 3;                      // tile row 0..127
      const int gc = (ci & 7) ^ (r & 7);           // swizzled source chunk
      const __hip_bfloat16* ga = A  + (aRow0 + r) * HID + kt * 64 + gc * 8;
      const __hip_bfloat16* gb = BT + (bRow0 + r) * HID + kt * 64 + gc * 8;
      GLOAD_LDS16(ga, &As[(q * 256 + wave * 64) * 8]);
      GLOAD_LDS16(gb, &Bs[(q * 256 + wave * 64) * 8]);
    }
    __syncthreads();

    s16x8 af[2][4], bf[2][4];
#pragma unroll
    for (int kc = 0; kc < 2; ++kc) {
      const int cc = kc * 4 + (lane >> 4);
#pragma unroll
      for (int m = 0; m < 4; ++m) {
        const int rowA = wm * 64 + m * 16 + l16;
        af[kc][m] = *reinterpret_cast<const s16x8*>(&As[rowA * 64 + ((cc ^ (rowA & 7)) * 8)]);
      }
#pragma unroll
      for (int n = 0; n < 4; ++n) {
        const int rowB = wn * 64 + n * 16 + l16;
        bf[kc][n] = *reinterpret_cast<const s16x8*>(&Bs[rowB * 64 + ((cc ^ (rowB & 7)) * 8)]);
      }
    }
#pragma unroll
    for (int kc = 0; kc < 2; ++kc)
#pragma unroll
      for (int m = 0; m < 4; ++m)
#pragma unroll
        for (int n = 0; n < 4; ++n)
          acc[m][n] = __builtin_amdgcn_mfma_f32_16x16x32_bf16(af[kc][m], bf[kc][n], acc[m][n], 0, 0, 0);
  }

  const int crow0 = by * 128 + wm * 64 + (lane >> 4) * 4;
  const int ccol0 = bx * 128 + wn * 64 + l16;
#pragma unroll
  for (int n = 0; n < 4; ++n) {
    const int ccol = ccol0 + n * 16;
    if (ccol < OUTN) {
      const float bq = b_q[ccol];
#pragma unroll
      for (int m = 0; m < 4; ++m) {
        const int crow = crow0 + m * 16;
#pragma unroll
        for (int j = 0; j < 4; ++j)
          Y[(size_t)(crow + j) * OUTN + ccol] = acc[m][n][j] + bq;
      }
    }
  }
}

// ---------------------------------------------------------------- launch
extern "C" void kernel_launch(void* const* d_in, const int* in_sizes, int n_in,
                              void* d_out, int out_size, void* d_ws, size_t ws_size,
                              hipStream_t stream) {
  const int*   inputs = (const int*)d_in[0];
  const float* state  = (const float*)d_in[1];
  const float* W_xh   = (const float*)d_in[2];
  const float* W_hh   = (const float*)d_in[3];
  const float* b_h    = (const float*)d_in[4];
  const float* W_hq   = (const float*)d_in[5];
  const float* b_q    = (const float*)d_in[6];

  float* Y    = (float*)d_out;                        // [8192][10000]
  float* Hfin = Y + (size_t)SEQT * BATCH * OUTN;      // [32][1024]

  char* ws = (char*)d_ws;
  // Hbf: 257 slots of [32][1024] bf16; slot 0 = state, slot t+1 = H_t
  __hip_bfloat16* Hbf  = (__hip_bfloat16*)ws;                                   // 16,842,752 B
  __hip_bfloat16* WhhT = (__hip_bfloat16*)(ws + 16842752);                      //  2,097,152 B
  __hip_bfloat16* WhqT = (__hip_bfloat16*)(ws + 16842752 + 2097152);            // 20,709,376 B

  transpose_cast<<<dim3(32, 32), 256, 0, stream>>>(W_hh, WhhT, HID, HID, HID);
  transpose_cast<<<dim3(NPAD / 32, 32), 256, 0, stream>>>(W_hq, WhqT, HID, OUTN, NPAD);
  cast_state<<<dim3(BATCH * HID / 256), 256, 0, stream>>>(state, Hbf, BATCH * HID);

  {
    void* args[] = {(void*)&Hbf, (void*)&inputs, (void*)&W_xh,
                    (void*)&WhhT, (void*)&b_h, (void*)&Hfin};
    hipLaunchCooperativeKernel((const void*)rnn_persist, dim3(32), dim3(256),
                               args, 0, stream);
  }

  // A rows r = t*32+b  <->  Hbf slot t+1 row b  ==  Hbf + (r+32)*1024
  gemm_out<<<dim3(NPAD / 128, 8192 / 128), 256, 0, stream>>>(Hbf + BATCH * HID, WhqT, b_q, Y);
}

// Round 4
// 1936.526 us; speedup vs baseline: 1.8334x; 1.5706x over previous
//
#include <hip/hip_runtime.h>
#include <hip/hip_bf16.h>

#define VOCAB 10000
#define HID   1024
#define OUTN  10000
#define BATCH 32
#define SEQT  256
#define NPAD  10112   // 79*128

typedef short s16x8 __attribute__((ext_vector_type(8)));
typedef float f32x4 __attribute__((ext_vector_type(4)));

#define GLOAD_LDS16(gptr, lptr)                                                      \
  __builtin_amdgcn_global_load_lds((__attribute__((address_space(1))) void*)(gptr),  \
                                   (__attribute__((address_space(3))) void*)(lptr),  \
                                   16, 0, 0)

// ---------------------------------------------------------------- transpose+cast
// src [K][N] f32 row-major  ->  dst [Npad][K] bf16 (rows n>=N zero-filled)
__global__ __launch_bounds__(256) void transpose_cast(
    const float* __restrict__ src, __hip_bfloat16* __restrict__ dst,
    int K, int N, int Npad) {
  __shared__ float tile[32][33];
  const int n0 = blockIdx.x * 32, k0 = blockIdx.y * 32;
  const int tx = threadIdx.x & 31, ty = threadIdx.x >> 5;  // 32 x 8
#pragma unroll
  for (int yy = 0; yy < 32; yy += 8) {
    const int k = k0 + ty + yy, n = n0 + tx;
    tile[ty + yy][tx] = (k < K && n < N) ? src[k * N + n] : 0.f;
  }
  __syncthreads();
#pragma unroll
  for (int yy = 0; yy < 32; yy += 8) {
    const int n = n0 + ty + yy, k = k0 + tx;
    if (n < Npad && k < K) dst[(size_t)n * K + k] = __float2bfloat16(tile[tx][ty + yy]);
  }
}

// also zero-inits the barrier counter each launch (replay-safe, device-scope)
__global__ __launch_bounds__(256) void cast_state(
    const float* __restrict__ s, __hip_bfloat16* __restrict__ d, int n,
    unsigned* __restrict__ counter) {
  const int i = blockIdx.x * 256 + threadIdx.x;
  if (i == 0) atomicExch(counter, 0u);
  if (i < n) d[i] = __float2bfloat16(s[i]);
}

// ---------------------------------------------------------------- coherent access helpers
__device__ __forceinline__ s16x8 load16_coherent(const void* p) {
  s16x8 v;
  asm volatile("global_load_dwordx4 %0, %1, off sc0 sc1"
               : "=v"(v) : "v"(p) : "memory");
  return v;
}
__device__ __forceinline__ void store2_coherent(void* p, unsigned short h) {
  unsigned u = h;
  asm volatile("global_store_short %0, %1, off sc0 sc1"
               :: "v"(p), "v"(u) : "memory");
}

// ---------------------------------------------------------------- persistent recurrence
// NORMAL launch (32 WGs x 256 thr; 32 WGs << 256 CUs => all co-resident; no
// cooperative launch needed since the barrier is hand-rolled). WG owns 32 cols,
// waves 2x2 over (32 rows x 32 cols). WhhT slice lives in registers (128 VGPR,
// 1 wave/SIMD). Cross-WG sync: monotone atomic counter; H traffic via sc0/sc1
// (device-scope write-through / L1-L2-bypass reads) so no cache flushes needed
// and W_xh/ids stay L2-resident.
__global__ __launch_bounds__(256, 1) void rnn_persist(
    __hip_bfloat16* __restrict__ Hbf,          // 257 slots of [32][1024] bf16
    const int* __restrict__ ids,               // [BATCH][SEQT]
    const float* __restrict__ W_xh,            // [VOCAB][HID] f32
    const __hip_bfloat16* __restrict__ WhhT,   // [HID][HID] bf16, [n][k]
    const float* __restrict__ b_h,
    float* __restrict__ Hfin,                  // [32][1024] f32 (tail of d_out)
    unsigned* __restrict__ counter) {
  const int wg   = blockIdx.x;
  const int wave = threadIdx.x >> 6;
  const int lane = threadIdx.x & 63;
  const int wm = wave >> 1, wn = wave & 1;
  const int row0 = wm * 16;
  const int col0 = wg * 32 + wn * 16;
  const int l16 = lane & 15;
  const int g   = lane >> 4;

  // ---- hoist B (WhhT slice) into registers: 32 frags = 128 VGPR (no calls => stays)
  s16x8 breg[32];
  {
    const __hip_bfloat16* bBase = WhhT + (size_t)(col0 + l16) * HID + g * 8;
#pragma unroll
    for (int kk = 0; kk < 32; ++kk)
      breg[kk] = *reinterpret_cast<const s16x8*>(bBase + kk * 32);
  }

  // C/D layout: col = lane&15, row = (lane>>4)*4 + j   [m89]
  const int ccol  = col0 + l16;
  const int crow0 = row0 + g * 4;
  const float bh = b_h[ccol];

  // ---- prefetch W_xh gather for t=0 (normal cached loads)
  float wxh[4];
#pragma unroll
  for (int j = 0; j < 4; ++j)
    wxh[j] = W_xh[(size_t)ids[(crow0 + j) * SEQT + 0] * HID + ccol];

  const int aOff = (row0 + l16) * HID + g * 8;

  for (int t = 0; t < SEQT; ++t) {
    const __hip_bfloat16* aBase = Hbf + (size_t)t * BATCH * HID + aOff;
    __hip_bfloat16* Hnext = Hbf + (size_t)(t + 1) * BATCH * HID;

    // issue all 32 A loads (device-scope, pipelined; one latency + drain)
    s16x8 areg[32];
#pragma unroll
    for (int kk = 0; kk < 32; ++kk)
      areg[kk] = load16_coherent(aBase + kk * 32);
    asm volatile("s_waitcnt vmcnt(0)" ::: "memory");
    __builtin_amdgcn_sched_barrier(0);

    f32x4 acc0 = {0.f, 0.f, 0.f, 0.f}, acc1 = {0.f, 0.f, 0.f, 0.f};
#pragma unroll
    for (int kk = 0; kk < 32; kk += 2) {
      acc0 = __builtin_amdgcn_mfma_f32_16x16x32_bf16(areg[kk],     breg[kk],     acc0, 0, 0, 0);
      acc1 = __builtin_amdgcn_mfma_f32_16x16x32_bf16(areg[kk + 1], breg[kk + 1], acc1, 0, 0, 0);
    }

#pragma unroll
    for (int j = 0; j < 4; ++j) {
      const float x = acc0[j] + acc1[j] + wxh[j] + bh;
      // fast tanh: 1 - 2/(e^{2x}+1)  (monotone-safe at extremes)
      const float e = __expf(2.f * x);
      const float v = 1.f - 2.f / (e + 1.f);
      const __hip_bfloat16 hv = __float2bfloat16(v);
      store2_coherent(Hnext + (crow0 + j) * HID + ccol,
                      *reinterpret_cast<const unsigned short*>(&hv));
      if (t == SEQT - 1) Hfin[(crow0 + j) * HID + ccol] = v;
    }

    // prefetch next step's W_xh gather (H-independent); completes during barrier
    if (t + 1 < SEQT) {
#pragma unroll
      for (int j = 0; j < 4; ++j)
        wxh[j] = W_xh[(size_t)ids[(crow0 + j) * SEQT + (t + 1)] * HID + ccol];
    }

    if (t + 1 < SEQT) {
      // __syncthreads drains all waves' vmem (incl. sc0sc1 H stores) before barrier
      __syncthreads();
      if (threadIdx.x == 0) {
        atomicAdd(counter, 1u);                       // device-scope
        const unsigned target = 32u * (unsigned)(t + 1);
        unsigned v;
        do {
          asm volatile("global_load_dword %0, %1, off sc0 sc1\n\t"
                       "s_waitcnt vmcnt(0)"
                       : "=v"(v) : "v"(counter) : "memory");
        } while (v < target);
      }
      __syncthreads();
    }
  }
}

// ---------------------------------------------------------------- output GEMM
// Y[r][n] = sum_k A[r][k]*BT[n][k] + b_q[n]; A=[8192][1024], BT=[10112][1024]
// 128x128 tile, BK=64, 4 waves (2x2, 64x64 each, 4x4 frags of 16x16)
__global__ __launch_bounds__(256) void gemm_out(
    const __hip_bfloat16* __restrict__ A,
    const __hip_bfloat16* __restrict__ BT,
    const float* __restrict__ b_q,
    float* __restrict__ Y) {
  __shared__ __align__(16) __hip_bfloat16 As[128 * 64];
  __shared__ __align__(16) __hip_bfloat16 Bs[128 * 64];

  const int bx = blockIdx.x;   // n tile 0..78
  const int by = blockIdx.y;   // m tile 0..63
  const int wave = threadIdx.x >> 6;
  const int lane = threadIdx.x & 63;
  const int wm = wave >> 1, wn = wave & 1;
  const int l16 = lane & 15;

  const size_t aRow0 = (size_t)by * 128;
  const size_t bRow0 = (size_t)bx * 128;

  f32x4 acc[4][4];
#pragma unroll
  for (int m = 0; m < 4; ++m)
#pragma unroll
    for (int n = 0; n < 4; ++n) acc[m][n] = (f32x4){0.f, 0.f, 0.f, 0.f};

  for (int kt = 0; kt < HID / 64; ++kt) {
    __syncthreads();
    // stage: LDS linear dest, inverse-swizzled global source (rule 21)
#pragma unroll
    for (int q = 0; q < 4; ++q) {
      const int ci = q * 256 + wave * 64 + lane;   // chunk 0..1023 (16B each)
      const int r  = ci >> 3;                      // tile row 0..127
      const int gc = (ci & 7) ^ (r & 7);           // swizzled source chunk
      const __hip_bfloat16* ga = A  + (aRow0 + r) * HID + kt * 64 + gc * 8;
      const __hip_bfloat16* gb = BT + (bRow0 + r) * HID + kt * 64 + gc * 8;
      GLOAD_LDS16(ga, &As[(q * 256 + wave * 64) * 8]);
      GLOAD_LDS16(gb, &Bs[(q * 256 + wave * 64) * 8]);
    }
    __syncthreads();

    s16x8 af[2][4], bf[2][4];
#pragma unroll
    for (int kc = 0; kc < 2; ++kc) {
      const int cc = kc * 4 + (lane >> 4);
#pragma unroll
      for (int m = 0; m < 4; ++m) {
        const int rowA = wm * 64 + m * 16 + l16;
        af[kc][m] = *reinterpret_cast<const s16x8*>(&As[rowA * 64 + ((cc ^ (rowA & 7)) * 8)]);
      }
#pragma unroll
      for (int n = 0; n < 4; ++n) {
        const int rowB = wn * 64 + n * 16 + l16;
        bf[kc][n] = *reinterpret_cast<const s16x8*>(&Bs[rowB * 64 + ((cc ^ (rowB & 7)) * 8)]);
      }
    }
#pragma unroll
    for (int kc = 0; kc < 2; ++kc)
#pragma unroll
      for (int m = 0; m < 4; ++m)
#pragma unroll
        for (int n = 0; n < 4; ++n)
          acc[m][n] = __builtin_amdgcn_mfma_f32_16x16x32_bf16(af[kc][m], bf[kc][n], acc[m][n], 0, 0, 0);
  }

  const int crow0 = by * 128 + wm * 64 + (lane >> 4) * 4;
  const int ccol0 = bx * 128 + wn * 64 + l16;
#pragma unroll
  for (int n = 0; n < 4; ++n) {
    const int ccol = ccol0 + n * 16;
    if (ccol < OUTN) {
      const float bq = b_q[ccol];
#pragma unroll
      for (int m = 0; m < 4; ++m) {
        const int crow = crow0 + m * 16;
#pragma unroll
        for (int j = 0; j < 4; ++j)
          Y[(size_t)(crow + j) * OUTN + ccol] = acc[m][n][j] + bq;
      }
    }
  }
}

// ---------------------------------------------------------------- launch
extern "C" void kernel_launch(void* const* d_in, const int* in_sizes, int n_in,
                              void* d_out, int out_size, void* d_ws, size_t ws_size,
                              hipStream_t stream) {
  const int*   inputs = (const int*)d_in[0];
  const float* state  = (const float*)d_in[1];
  const float* W_xh   = (const float*)d_in[2];
  const float* W_hh   = (const float*)d_in[3];
  const float* b_h    = (const float*)d_in[4];
  const float* W_hq   = (const float*)d_in[5];
  const float* b_q    = (const float*)d_in[6];

  float* Y    = (float*)d_out;                        // [8192][10000]
  float* Hfin = Y + (size_t)SEQT * BATCH * OUTN;      // [32][1024]

  char* ws = (char*)d_ws;
  // Hbf: 257 slots of [32][1024] bf16; slot 0 = state, slot t+1 = H_t
  __hip_bfloat16* Hbf  = (__hip_bfloat16*)ws;                                   // 16,842,752 B
  __hip_bfloat16* WhhT = (__hip_bfloat16*)(ws + 16842752);                      //  2,097,152 B
  __hip_bfloat16* WhqT = (__hip_bfloat16*)(ws + 16842752 + 2097152);            // 20,709,376 B
  // barrier counter: last 128 B of WhqT's zero-pad rows (row 10111 >= OUTN --
  // feeds only discarded GEMM columns). Stays within the round-1/2-proven ws
  // footprint. Zeroed by transpose_cast's pad-fill AND by cast_state.
  unsigned* counter    = (unsigned*)(ws + 16842752 + 2097152 + 20709376 - 128);

  transpose_cast<<<dim3(32, 32), 256, 0, stream>>>(W_hh, WhhT, HID, HID, HID);
  transpose_cast<<<dim3(NPAD / 32, 32), 256, 0, stream>>>(W_hq, WhqT, HID, OUTN, NPAD);
  cast_state<<<dim3(BATCH * HID / 256), 256, 0, stream>>>(state, Hbf, BATCH * HID, counter);

  rnn_persist<<<dim3(32), dim3(256), 0, stream>>>(
      Hbf, inputs, W_xh, WhhT, b_h, Hfin, counter);

  // A rows r = t*32+b  <->  Hbf slot t+1 row b  ==  Hbf + (r+32)*1024
  gemm_out<<<dim3(NPAD / 128, 8192 / 128), 256, 0, stream>>>(Hbf + BATCH * HID, WhqT, b_q, Y);
}